// Round 4
// baseline (2844.008 us; speedup 1.0000x reference)
//
#include <hip/hip_runtime.h>
#include <hip/hip_bf16.h>
#include <math.h>

#define DD 4096
#define STEPS 16
#define KSPLIT 128
#define KSPLIT_E 32

__device__ __forceinline__ float gelu_exact(float x) {
    return 0.5f * x * (1.0f + erff(x * 0.70710678118654752f));
}
__device__ __forceinline__ float sigmoidf_(float x) {
    return 1.0f / (1.0f + expf(-x));
}

// ---------------------------------------------------------------------------
// Column matvec: y[n] = sum_k x[k] * W[k*N + n]; K split across gridDim.y
// (K = chunk * gridDim.y). x is produced "virtually" in LDS:
//   mode 0: x[k] = p0[k]
//   mode 1: fusion(a=p0, p=p1, c=p2): [a, p, c, p-a, p*a]   (chunk=160)
//   mode 3: x[k] = GELU(bias_in[k] + aux[k]? + sum_j partials_in[j*DD+k]) (chunk=32)
//           -- fuses previous layer's reduce+bias(+cond+emb)+GELU into staging.
// Each thread accumulates 4 consecutive columns (float4 loads).
// ---------------------------------------------------------------------------
__global__ __launch_bounds__(256) void mv_col_kernel(
    const float* __restrict__ p0, const float* __restrict__ p1,
    const float* __restrict__ p2, int mode,
    const float* __restrict__ partials_in, const float* __restrict__ bias_in,
    const float* __restrict__ aux,
    const float* __restrict__ W, int N, int chunk,
    float* __restrict__ partials_out)
{
    __shared__ float xs[160];      // max chunk
    __shared__ float xp[8][32];    // mode-3 partial reduce
    const int k0 = blockIdx.y * chunk;

    if (mode == 3) {
        // 256 threads: element i = tid&31, slice sl = tid>>5 sums 16 of 128 rows
        const int i = threadIdx.x & 31, sl = threadIdx.x >> 5;
        const int k = k0 + i;
        float a = 0.f;
        #pragma unroll
        for (int j = 0; j < 16; ++j)
            a += partials_in[(size_t)(sl * 16 + j) * DD + k];
        xp[sl][i] = a;
        __syncthreads();
        if (threadIdx.x < 32) {
            int kk = k0 + threadIdx.x;
            float v = bias_in[kk];
            if (aux) v += aux[kk];
            #pragma unroll
            for (int s2 = 0; s2 < 8; ++s2) v += xp[s2][threadIdx.x];
            xs[threadIdx.x] = gelu_exact(v);
        }
    } else {
        for (int i = threadIdx.x; i < chunk; i += 256) {
            int k = k0 + i;
            float v;
            if (mode == 0) {
                v = p0[k];
            } else {
                int seg = k >> 12, j = k & 4095;
                if      (seg == 0) v = p0[j];
                else if (seg == 1) v = p1[j];
                else if (seg == 2) v = p2[j];
                else if (seg == 3) v = p1[j] - p0[j];
                else               v = p1[j] * p0[j];
            }
            xs[i] = v;
        }
    }
    __syncthreads();

    const int col = (blockIdx.x * 256 + threadIdx.x) * 4;
    const float* wp = W + (size_t)k0 * N + col;
    float4 acc = make_float4(0.f, 0.f, 0.f, 0.f);
    #pragma unroll 8
    for (int i = 0; i < chunk; ++i) {
        float xv = xs[i];
        float4 w = *reinterpret_cast<const float4*>(wp);
        wp += N;
        acc.x += xv * w.x; acc.y += xv * w.y;
        acc.z += xv * w.z; acc.w += xv * w.w;
    }
    *reinterpret_cast<float4*>(partials_out + (size_t)blockIdx.y * N + col) = acc;
}

// Sum KSPLIT partials + bias, optional residual add.
__global__ __launch_bounds__(256) void reduce_kernel(
    const float* __restrict__ partials, int N,
    const float* __restrict__ bias,
    const float* __restrict__ res, float res_scale,
    float* __restrict__ out)
{
    int n = blockIdx.x * 256 + threadIdx.x;
    float acc = bias[n];
    #pragma unroll 8
    for (int j = 0; j < KSPLIT; ++j) acc += partials[(size_t)j * N + n];
    if (res) acc = res[n] + res_scale * acc;
    out[n] = acc;
}

// ---------------------------------------------------------------------------
// Batched emb pass: pre_emb[t][n] = sum_k emb[t][k] * W1e[k*N + n], 16 t at once.
// ONE streaming pass over W1e instead of 16. grid (DD/1024, KSPLIT_E), chunk=128.
// ---------------------------------------------------------------------------
__global__ __launch_bounds__(256) void mv_emb_kernel(
    const float* __restrict__ emb, const float* __restrict__ W, int N,
    float* __restrict__ partials_out)
{
    __shared__ float xs[128][16];
    const int chunk = 128;
    const int k0 = blockIdx.y * chunk;
    for (int idx = threadIdx.x; idx < chunk * 16; idx += 256) {
        int kl = idx >> 4, t = idx & 15;
        xs[kl][t] = emb[(size_t)t * DD + k0 + kl];
    }
    __syncthreads();

    const int col = (blockIdx.x * 256 + threadIdx.x) * 4;
    const float* wp = W + (size_t)k0 * N + col;
    float4 acc[16];
    #pragma unroll
    for (int t = 0; t < 16; ++t) acc[t] = make_float4(0.f, 0.f, 0.f, 0.f);
    for (int i = 0; i < chunk; ++i) {
        float4 w = *reinterpret_cast<const float4*>(wp);
        wp += N;
        #pragma unroll
        for (int t = 0; t < 16; ++t) {
            float xv = xs[i][t];
            acc[t].x += xv * w.x; acc[t].y += xv * w.y;
            acc[t].z += xv * w.z; acc[t].w += xv * w.w;
        }
    }
    #pragma unroll
    for (int t = 0; t < 16; ++t)
        *reinterpret_cast<float4*>(partials_out +
            ((size_t)blockIdx.y * 16 + t) * DD + col) = acc[t];
}

// pre_emb[t*DD+n] = sum_s partials[(s*16+t)*DD + n]  (s < KSPLIT_E)
__global__ __launch_bounds__(256) void reduce_emb_kernel(
    const float* __restrict__ partials, float* __restrict__ pre_emb)
{
    int n = blockIdx.x * 256 + threadIdx.x;
    int t = blockIdx.y;
    float acc = 0.f;
    #pragma unroll 8
    for (int s = 0; s < KSPLIT_E; ++s)
        acc += partials[((size_t)s * 16 + t) * DD + n];
    pre_emb[(size_t)t * DD + n] = acc;
}

// ---------------------------------------------------------------------------
// GRU step: one wave per output element d; 6 contiguous row-dots of length 4096.
// x, s are 16 KB each and L1/L2-resident -> read straight from global.
// r/z gates are linear in gi+gh, so those partials are combined BEFORE the
// butterfly: only 4 reduction trees (r, z, inn, hn) instead of 6.
// ---------------------------------------------------------------------------
__global__ __launch_bounds__(256) void gru_kernel(
    const float* __restrict__ x, const float* __restrict__ s,
    const float* __restrict__ w_ih, const float* __restrict__ b_ih,
    const float* __restrict__ w_hh, const float* __restrict__ b_hh,
    float* __restrict__ h_out)
{
    const int wave = threadIdx.x >> 6, lane = threadIdx.x & 63;
    const int d = blockIdx.x * 4 + wave;

    const float4* x4 = reinterpret_cast<const float4*>(x);
    const float4* s4 = reinterpret_cast<const float4*>(s);
    const float4* rows[6] = {
        reinterpret_cast<const float4*>(w_ih + (size_t)d * DD),
        reinterpret_cast<const float4*>(w_ih + (size_t)(DD + d) * DD),
        reinterpret_cast<const float4*>(w_ih + (size_t)(2 * DD + d) * DD),
        reinterpret_cast<const float4*>(w_hh + (size_t)d * DD),
        reinterpret_cast<const float4*>(w_hh + (size_t)(DD + d) * DD),
        reinterpret_cast<const float4*>(w_hh + (size_t)(2 * DD + d) * DD)
    };
    float acc[6];
    #pragma unroll
    for (int r = 0; r < 6; ++r) {
        const float4* vv = (r < 3) ? x4 : s4;
        float a = 0.f;
        #pragma unroll
        for (int i = 0; i < 16; ++i) {
            float4 w = rows[r][i * 64 + lane];
            float4 v = vv[i * 64 + lane];
            a += w.x * v.x + w.y * v.y + w.z * v.z + w.w * v.w;
        }
        acc[r] = a;
    }
    float c0 = acc[0] + acc[3];   // r pre-act (biases added after reduce)
    float c1 = acc[1] + acc[4];   // z pre-act
    float c2 = acc[2];            // inn
    float c5 = acc[5];            // hn
    #pragma unroll
    for (int off = 32; off > 0; off >>= 1) {
        c0 += __shfl_down(c0, off, 64);
        c1 += __shfl_down(c1, off, 64);
        c2 += __shfl_down(c2, off, 64);
        c5 += __shfl_down(c5, off, 64);
    }
    if (lane == 0) {
        float r  = sigmoidf_(c0 + b_ih[d] + b_hh[d]);
        float z  = sigmoidf_(c1 + b_ih[DD + d] + b_hh[DD + d]);
        float hn = c5 + b_hh[2 * DD + d];
        float nn = tanhf(c2 + b_ih[2 * DD + d] + r * hn);
        h_out[d] = (1.f - z) * nn + z * s[d];
    }
}

// LayerNorm over 4096 elems; block b normalizes row b.
__global__ __launch_bounds__(256) void ln_kernel(
    const float* __restrict__ h_base, const float* __restrict__ g,
    const float* __restrict__ b, float* __restrict__ out_base)
{
    const float* h = h_base + (size_t)blockIdx.x * DD;
    float* out = out_base + (size_t)blockIdx.x * DD;
    __shared__ float rs[4], rq[4];
    float4 v[4];
    float sum = 0.f, sq = 0.f;
    #pragma unroll
    for (int i = 0; i < 4; ++i) {
        v[i] = reinterpret_cast<const float4*>(h)[i * 256 + threadIdx.x];
        sum += v[i].x + v[i].y + v[i].z + v[i].w;
        sq  += v[i].x * v[i].x + v[i].y * v[i].y + v[i].z * v[i].z + v[i].w * v[i].w;
    }
    #pragma unroll
    for (int off = 32; off > 0; off >>= 1) {
        sum += __shfl_down(sum, off, 64);
        sq  += __shfl_down(sq,  off, 64);
    }
    int wave = threadIdx.x >> 6, lane = threadIdx.x & 63;
    if (lane == 0) { rs[wave] = sum; rq[wave] = sq; }
    __syncthreads();
    float ts = rs[0] + rs[1] + rs[2] + rs[3];
    float tq = rq[0] + rq[1] + rq[2] + rq[3];
    float mu = ts * (1.f / 4096.f);
    float var = tq * (1.f / 4096.f) - mu * mu;
    float rstd = rsqrtf(var + 1e-5f);
    #pragma unroll
    for (int i = 0; i < 4; ++i) {
        int idx = i * 256 + threadIdx.x;
        float4 gv = reinterpret_cast<const float4*>(g)[idx];
        float4 bv = reinterpret_cast<const float4*>(b)[idx];
        float4 o;
        o.x = (v[i].x - mu) * rstd * gv.x + bv.x;
        o.y = (v[i].y - mu) * rstd * gv.y + bv.y;
        o.z = (v[i].z - mu) * rstd * gv.z + bv.z;
        o.w = (v[i].w - mu) * rstd * gv.w + bv.w;
        reinterpret_cast<float4*>(out)[idx] = o;
    }
}

// gate[t] = sigmoid([states_t, cond] @ gate_w + gate_b); summary = sum g*s / max(sum g,1e-6)
__global__ __launch_bounds__(1024) void gate_summary_kernel(
    const float* __restrict__ states, const float* __restrict__ condition,
    const float* __restrict__ gate_w, const float* __restrict__ gate_b,
    float* __restrict__ summary)
{
    __shared__ float gsh[16];
    const int wave = threadIdx.x >> 6, lane = threadIdx.x & 63;
    const float4* st4 = reinterpret_cast<const float4*>(states) + (size_t)wave * 1024;
    const float4* c4  = reinterpret_cast<const float4*>(condition);
    const float4* gw4 = reinterpret_cast<const float4*>(gate_w);
    float a = 0.f;
    #pragma unroll
    for (int i = 0; i < 16; ++i) {
        float4 xv = st4[i * 64 + lane];
        float4 wv = gw4[i * 64 + lane];
        a += xv.x * wv.x + xv.y * wv.y + xv.z * wv.z + xv.w * wv.w;
    }
    #pragma unroll
    for (int i = 0; i < 16; ++i) {
        float4 xv = c4[i * 64 + lane];
        float4 wv = gw4[1024 + i * 64 + lane];
        a += xv.x * wv.x + xv.y * wv.y + xv.z * wv.z + xv.w * wv.w;
    }
    #pragma unroll
    for (int off = 32; off > 0; off >>= 1) a += __shfl_down(a, off, 64);
    if (lane == 0) gsh[wave] = sigmoidf_(a + gate_b[0]);
    __syncthreads();

    float gsum = 0.f;
    #pragma unroll
    for (int t = 0; t < 16; ++t) gsum += gsh[t];
    float inv = 1.f / fmaxf(gsum, 1e-6f);

    float4 acc = make_float4(0.f, 0.f, 0.f, 0.f);
    #pragma unroll
    for (int t = 0; t < 16; ++t) {
        float4 sv = reinterpret_cast<const float4*>(states)[(size_t)t * 1024 + threadIdx.x];
        float gt = gsh[t];
        acc.x += gt * sv.x; acc.y += gt * sv.y;
        acc.z += gt * sv.z; acc.w += gt * sv.w;
    }
    acc.x *= inv; acc.y *= inv; acc.z *= inv; acc.w *= inv;
    reinterpret_cast<float4*>(summary)[threadIdx.x] = acc;
}

extern "C" void kernel_launch(void* const* d_in, const int* in_sizes, int n_in,
                              void* d_out, int out_size, void* d_ws, size_t ws_size,
                              hipStream_t stream) {
    const float* a        = (const float*)d_in[0];
    const float* p        = (const float*)d_in[1];
    const float* c        = (const float*)d_in[2];
    const float* seed_w1  = (const float*)d_in[3];
    const float* seed_b1  = (const float*)d_in[4];
    const float* seed_w2  = (const float*)d_in[5];
    const float* seed_b2  = (const float*)d_in[6];
    const float* cond_w1  = (const float*)d_in[7];
    const float* cond_b1  = (const float*)d_in[8];
    const float* cond_w2  = (const float*)d_in[9];
    const float* cond_b2  = (const float*)d_in[10];
    const float* in_w1    = (const float*)d_in[11];
    const float* in_b1    = (const float*)d_in[12];
    const float* in_w2    = (const float*)d_in[13];
    const float* in_b2    = (const float*)d_in[14];
    const float* step_emb = (const float*)d_in[15];
    const float* w_ih     = (const float*)d_in[16];
    const float* b_ih     = (const float*)d_in[17];
    const float* w_hh     = (const float*)d_in[18];
    const float* b_hh     = (const float*)d_in[19];
    const float* ln_g     = (const float*)d_in[20];
    const float* ln_b     = (const float*)d_in[21];
    const float* gate_w   = (const float*)d_in[22];
    const float* gate_b   = (const float*)d_in[23];

    // in_w1 row slices: [0,4096)=cond, [4096,8192)=state, [8192,12288)=emb
    const float* in_w1_c = in_w1;
    const float* in_w1_s = in_w1 + (size_t)DD * DD;
    const float* in_w1_e = in_w1 + (size_t)2 * DD * DD;

    float* out = (float*)d_out;                    // [16*4096 states][4096 summary]
    float* ws  = (float*)d_ws;
    float* partials1 = ws;                           // KSPLIT*DD            (2 MB)
    float* partials2 = partials1 + KSPLIT * DD;      // KSPLIT*DD            (2 MB)
    float* partialsE = partials2 + KSPLIT * DD;      // KSPLIT_E*16*DD       (8 MB)
    float* pre_cond  = partialsE + KSPLIT_E * 16 * DD; // DD
    float* pre_emb   = pre_cond + DD;                // 16*DD
    float* condition = pre_emb + STEPS * DD;         // DD
    float* xvec      = condition + DD;               // DD
    float* h_all     = xvec + DD;                    // (STEPS+1)*DD

    const dim3 mvGrid(DD / 1024, KSPLIT);
    const dim3 redGrid(DD / 256);

    // Batched emb pass (independent of everything): ONE pass over W1_e
    mv_emb_kernel<<<dim3(DD / 1024, KSPLIT_E), 256, 0, stream>>>(step_emb, in_w1_e, DD, partialsE);
    reduce_emb_kernel<<<dim3(DD / 256, STEPS), 256, 0, stream>>>(partialsE, pre_emb);

    // cond_proj MLP -> condition
    mv_col_kernel<<<mvGrid, 256, 0, stream>>>(a, p, c, 1, nullptr, nullptr, nullptr,
                                              cond_w1, DD, 5 * DD / KSPLIT, partials1);
    mv_col_kernel<<<mvGrid, 256, 0, stream>>>(nullptr, nullptr, nullptr, 3, partials1, cond_b1,
                                              nullptr, cond_w2, DD, DD / KSPLIT, partials2);
    reduce_kernel<<<redGrid, 256, 0, stream>>>(partials2, DD, cond_b2, nullptr, 0.f, condition);

    // pre_cond = cond @ W1_c + in_b1  (step-invariant part of input_proj layer 1)
    mv_col_kernel<<<mvGrid, 256, 0, stream>>>(condition, nullptr, nullptr, 0, nullptr, nullptr,
                                              nullptr, in_w1_c, DD, DD / KSPLIT, partials1);
    reduce_kernel<<<redGrid, 256, 0, stream>>>(partials1, DD, in_b1, nullptr, 0.f, pre_cond);

    // seed_proj MLP -> state0 = p + 0.1 * mlp
    mv_col_kernel<<<mvGrid, 256, 0, stream>>>(a, p, c, 1, nullptr, nullptr, nullptr,
                                              seed_w1, DD, 5 * DD / KSPLIT, partials1);
    mv_col_kernel<<<mvGrid, 256, 0, stream>>>(nullptr, nullptr, nullptr, 3, partials1, seed_b1,
                                              nullptr, seed_w2, DD, DD / KSPLIT, partials2);
    reduce_kernel<<<redGrid, 256, 0, stream>>>(partials2, DD, seed_b2, p, 0.1f, h_all);

    for (int t = 0; t < STEPS; ++t) {
        const float* hcur = h_all + (size_t)t * DD;
        float* hnext = h_all + (size_t)(t + 1) * DD;
        // layer-1 step-dependent part: state @ W1_s
        mv_col_kernel<<<mvGrid, 256, 0, stream>>>(hcur, nullptr, nullptr, 0, nullptr, nullptr,
                                                  nullptr, in_w1_s, DD, DD / KSPLIT, partials1);
        // layer-2 with fused staging: GELU(pre_cond + pre_emb[t] + partial-sum)
        mv_col_kernel<<<mvGrid, 256, 0, stream>>>(nullptr, nullptr, nullptr, 3, partials1, pre_cond,
                                                  pre_emb + (size_t)t * DD,
                                                  in_w2, DD, DD / KSPLIT, partials2);
        reduce_kernel<<<redGrid, 256, 0, stream>>>(partials2, DD, in_b2, nullptr, 0.f, xvec);
        // GRU cell
        gru_kernel<<<dim3(DD / 4), 256, 0, stream>>>(xvec, hcur, w_ih, b_ih, w_hh, b_hh, hnext);
    }

    // All LayerNorms at once (off the serial chain): states[t] = LN(h_{t+1})
    ln_kernel<<<dim3(STEPS), 256, 0, stream>>>(h_all + DD, ln_g, ln_b, out);

    gate_summary_kernel<<<dim3(1), 1024, 0, stream>>>(out, condition, gate_w, gate_b,
                                                      out + (size_t)STEPS * DD);
}